// Round 11
// baseline (386.003 us; speedup 1.0000x reference)
//
#include <hip/hip_runtime.h>

// AttnHGCN.forward_ui — 3-layer bipartite LightGCN-style propagation.
// R16 (on R15's 378us): build-phase cleanup. R15 analysis: gather is within
//     ~20% of its structural byte floor (table fetch x8 XCDs ~170MB at the
//     ~3TB/s random fabric rate) — leave it alone. The build (~130us vs
//     ~50us floor) is the lever:
//  (a) FWIN 512->1024 (FROWS=147): ALL windows now fit win_sort's LDS cap
//      (user ~2940, item ~5860 < WCAP 8192) — R15's item windows (11720)
//      took a global double-read fallback for 2/3 of the data. 1024 WGs
//      also load-balance better over 2-WG/CU slots.
//  (b) key = dl<<17 | src (side bit dropped — side is a function of dest
//      row; it was provably dead in win_sort).
//  (c) scanA/winscanC at 512-thr blocks (NFB=500736 -> 978 sums <= scanB's
//      1024); fineoff kernel eliminated (win_sort reads bases straight
//      from scanned blkfine). 10 launches (was 12).
//  Zero device-scope atomics; zero fp atomics (R12 lesson).

constexpr int N_USERS = 100000;
constexpr int N_ITEMS = 50000;
constexpr int CH      = 64;
constexpr int N_EDGES = 2000000;
constexpr int LAYERS  = 3;
constexpr int NROWS   = N_USERS + N_ITEMS;          // 150000 combined dest rows
constexpr int NDIR    = 2 * N_EDGES;                // 4M directed edges

constexpr int QEDGES  = N_EDGES / 4;                // 500000 int4 edge-quads
constexpr int NBLK    = (QEDGES + 1023) / 1024;     // 489 binning blocks

constexpr int FWIN    = 1024;                       // fine windows
constexpr int FROWS   = (NROWS + FWIN - 1) / FWIN;  // 147 rows per window
constexpr int NFB     = FWIN * NBLK;                // 500736 (win,block) counts

constexpr int WCAP    = 8192;                       // win_sort LDS entry cap

constexpr long long ITEM_ELEMS = (long long)N_ITEMS * CH;  // 3,200,000
constexpr long long USER_ELEMS = (long long)N_USERS * CH;  // 6,400,000
constexpr long long TOT_ELEMS  = ITEM_ELEMS + USER_ELEMS;  // 9,600,000

typedef int      v4i __attribute__((ext_vector_type(4)));
typedef float    v4f __attribute__((ext_vector_type(4)));
typedef float    v8f __attribute__((ext_vector_type(8)));
typedef _Float16 v4h __attribute__((ext_vector_type(4)));
typedef _Float16 v8h __attribute__((ext_vector_type(8)));

static __device__ __forceinline__ float w15_to_f(unsigned pk) {
  unsigned short us = (unsigned short)(pk & 0x7FFF);  // sign bit 0
  _Float16 h;
  __builtin_memcpy(&h, &us, 2);
  return (float)h;
}
static __device__ __forceinline__ unsigned pack_sw(int src, _Float16 hw) {
  unsigned short us;
  __builtin_memcpy(&us, &hw, 2);
  return ((unsigned)src << 15) | (us & 0x7FFF);
}

// ---------------- generic scans (512-wide) ----------------

__global__ __launch_bounds__(512) void scanA512(
    const int* __restrict__ in, int* __restrict__ out,
    int* __restrict__ blksums, int n) {
  __shared__ int sh[512];
  int t = threadIdx.x;
  int i = blockIdx.x * 512 + t;
  int v = (i < n) ? in[i] : 0;
  int x = v;
  sh[t] = x; __syncthreads();
  for (int d = 1; d < 512; d <<= 1) {
    int add = (t >= d) ? sh[t - d] : 0;
    __syncthreads();
    x += add; sh[t] = x;
    __syncthreads();
  }
  if (i < n) out[i] = x - v;  // exclusive within block
  if (t == 511) blksums[blockIdx.x] = x;
}

__global__ __launch_bounds__(1024) void scanB_kernel(int* __restrict__ blksums, int n2) {
  __shared__ int sh[1024];
  int t = threadIdx.x;
  int v = (t < n2) ? blksums[t] : 0;
  int x = v;
  sh[t] = x; __syncthreads();
  for (int d = 1; d < 1024; d <<= 1) {
    int add = (t >= d) ? sh[t - d] : 0;
    __syncthreads();
    x += add; sh[t] = x;
    __syncthreads();
  }
  if (t < n2) blksums[t] = x - v;  // exclusive
}

__global__ __launch_bounds__(512) void winscanC512(
    int* __restrict__ out, const int* __restrict__ blksums, int n) {
  int i = blockIdx.x * 512 + threadIdx.x;
  if (i < n) out[i] += blksums[i >> 9];
}

// ---------------- window binning (zero device atomics; int LDS only) ----

__global__ __launch_bounds__(1024) void bincnt1024(
    const int* __restrict__ u_idx, const int* __restrict__ i_idx,
    int* __restrict__ blkfine) {
  __shared__ int cnt[FWIN];
  const int t = threadIdx.x;
  cnt[t] = 0;
  __syncthreads();
  int q = blockIdx.x * 1024 + t;
  if (q < QEDGES) {
    v4i u  = *(const v4i*)(u_idx + 4 * (long long)q);
    v4i it = *(const v4i*)(i_idx + 4 * (long long)q);
    atomicAdd(&cnt[u.x / FROWS], 1);
    atomicAdd(&cnt[u.y / FROWS], 1);
    atomicAdd(&cnt[u.z / FROWS], 1);
    atomicAdd(&cnt[u.w / FROWS], 1);
    atomicAdd(&cnt[(N_USERS + it.x) / FROWS], 1);
    atomicAdd(&cnt[(N_USERS + it.y) / FROWS], 1);
    atomicAdd(&cnt[(N_USERS + it.z) / FROWS], 1);
    atomicAdd(&cnt[(N_USERS + it.w) / FROWS], 1);
  }
  __syncthreads();
  blkfine[(long long)t * NBLK + blockIdx.x] = cnt[t];
}

// Block-local counting sort by fine window, contiguous copy-out to scanned
// (win,block) bases. key = (dl<<17) | src  (dl<147 fits 8b, src<2^17).
__global__ __launch_bounds__(1024) void segwrite1024(
    const int* __restrict__ u_idx, const int* __restrict__ i_idx,
    const float* __restrict__ wv, const int* __restrict__ blkfine,
    int* __restrict__ segkey, _Float16* __restrict__ segw) {
  extern __shared__ char smem[];
  int*            skey = (int*)smem;                       // 8192
  _Float16*       sw   = (_Float16*)(skey + 8192);         // 8192
  unsigned short* sfin = (unsigned short*)(sw + 8192);     // 8192
  int*            cnt  = (int*)(sfin + 8192);              // 1024

  const int t   = threadIdx.x;
  const int blk = blockIdx.x;
  cnt[t] = 0;
  __syncthreads();

  int q = blk * 1024 + t;
  bool valid = (q < QEDGES);
  int key8[8], fin8[8], rank8[8];
  _Float16 hw8[8];
  if (valid) {
    v4i u  = *(const v4i*)(u_idx + 4 * (long long)q);
    v4i it = *(const v4i*)(i_idx + 4 * (long long)q);
    v4f w  = *(const v4f*)(wv + 4 * (long long)q);
    int rows[8], srcs[8];
    float ws[8];
    rows[0] = u.x; rows[1] = u.y; rows[2] = u.z; rows[3] = u.w;
    srcs[0] = it.x; srcs[1] = it.y; srcs[2] = it.z; srcs[3] = it.w;
    rows[4] = N_USERS + it.x; rows[5] = N_USERS + it.y;
    rows[6] = N_USERS + it.z; rows[7] = N_USERS + it.w;
    srcs[4] = u.x; srcs[5] = u.y; srcs[6] = u.z; srcs[7] = u.w;
    ws[0] = w.x; ws[1] = w.y; ws[2] = w.z; ws[3] = w.w;
    ws[4] = w.x; ws[5] = w.y; ws[6] = w.z; ws[7] = w.w;
#pragma unroll
    for (int k = 0; k < 8; ++k) {
      int fin = rows[k] / FROWS;
      int dl  = rows[k] - fin * FROWS;
      fin8[k]  = fin;
      key8[k]  = (dl << 17) | srcs[k];
      hw8[k]   = (_Float16)ws[k];
      rank8[k] = atomicAdd(&cnt[fin], 1);
    }
  }
  __syncthreads();

  // exclusive scan of cnt[0..1023] in place (all threads hit barriers)
  int v = cnt[t], x = v;
  for (int d = 1; d < 1024; d <<= 1) {
    int add = (t >= d) ? cnt[t - d] : 0;
    __syncthreads();
    x += add; cnt[t] = x;
    __syncthreads();
  }
  cnt[t] = x - v;  // exclusive base within block
  __syncthreads();

  if (valid) {
#pragma unroll
    for (int k = 0; k < 8; ++k) {
      int slot = cnt[fin8[k]] + rank8[k];
      skey[slot] = key8[k];
      sw[slot]   = hw8[k];
      sfin[slot] = (unsigned short)fin8[k];
    }
  }
  __syncthreads();

  const int ecount = 8 * min(1024, QEDGES - blk * 1024);
  for (int j = t; j < ecount; j += 1024) {
    int f = sfin[j];
    int gpos = blkfine[(long long)f * NBLK + blk] + (j - cnt[f]);
    segkey[gpos] = skey[j];
    segw[gpos]   = sw[j];
  }
}

// Per-window counting sort -> packed CSR (+ row_ptr). One 1024-thr WG per
// window (1024 WGs). All windows fit WCAP (max ~6300 expected); global
// 2-pass fallback retained for safety. Window bases read directly from the
// scanned blkfine (column 0 of each window's row).
__global__ __launch_bounds__(1024) void win_sort1024(
    const int* __restrict__ segkey, const _Float16* __restrict__ segw,
    const int* __restrict__ blkfine, int* __restrict__ row_ptr,
    unsigned* __restrict__ csrp) {
  __shared__ unsigned        lkey[WCAP];   // 32768 B
  __shared__ unsigned short  lwb[WCAP];    // 16384 B
  __shared__ int             hist[FWIN];   //  4096 B   (52KB total)
  const int w   = blockIdx.x;
  const int wlo = w * FROWS;
  const int wsz = min(FROWS, NROWS - wlo);     // may be <=0 for tail windows
  const int s0  = blkfine[(long long)w * NBLK];
  const int s1  = (w < FWIN - 1) ? blkfine[(long long)(w + 1) * NBLK] : NDIR;
  const int n   = s1 - s0;
  const bool inlds = (n <= WCAP);
  const int t   = threadIdx.x;

  hist[t] = 0;
  if (inlds) {
    for (int i = t; i < n; i += 1024) {
      lkey[i] = (unsigned)segkey[s0 + i];
      _Float16 h = segw[s0 + i];
      unsigned short us;
      __builtin_memcpy(&us, &h, 2);
      lwb[i] = us;
    }
  }
  __syncthreads();

  // pass A: histogram of dl
  if (inlds) {
    for (int i = t; i < n; i += 1024) atomicAdd(&hist[lkey[i] >> 17], 1);
  } else {
    for (int i = t; i < n; i += 1024)
      atomicAdd(&hist[((unsigned)segkey[s0 + i]) >> 17], 1);
  }
  __syncthreads();

  // exclusive scan of hist[0..1023]
  int v = hist[t], x = v;
  for (int d = 1; d < 1024; d <<= 1) {
    int add = (t >= d) ? hist[t - d] : 0;
    __syncthreads();
    x += add; hist[t] = x;
    __syncthreads();
  }
  __syncthreads();
  int base = x - v;  // exclusive prefix for slot t
  if (t < wsz) row_ptr[wlo + t] = s0 + base;
  if (w == FWIN - 1 && t == 0) row_ptr[NROWS] = NDIR;
  hist[t] = s0 + base;  // becomes cursor
  __syncthreads();

  // pass B: place (packed: src<<15 | w15; w>=0 so sign bit is 0)
  if (inlds) {
    for (int i = t; i < n; i += 1024) {
      unsigned key = lkey[i];
      int p = atomicAdd(&hist[key >> 17], 1);
      csrp[p] = ((key & 0x1FFFFu) << 15) | (lwb[i] & 0x7FFF);
    }
  } else {
    for (int i = t; i < n; i += 1024) {
      unsigned key = (unsigned)segkey[s0 + i];
      int p = atomicAdd(&hist[key >> 17], 1);
      csrp[p] = pack_sw(key & 0x1FFFF, segw[s0 + i]);
    }
  }
}

// ---------------- fp16 table conversion ----------------
__global__ __launch_bounds__(256) void cvt_tab(
    const float* __restrict__ it, const float* __restrict__ u,
    _Float16* __restrict__ t0) {
  long long i = (long long)blockIdx.x * 256 + threadIdx.x;  // float4 quads
  if (i >= TOT_ELEMS / 4) return;
  long long e = i * 4;
  const float* src = (e < ITEM_ELEMS) ? (it + e) : (u + (e - ITEM_ELEMS));
  v4f f = *(const v4f*)src;
  v4h h = {(_Float16)f.x, (_Float16)f.y, (_Float16)f.z, (_Float16)f.w};
  *(v4h*)(t0 + e) = h;
}

// ---------------- per-layer fused gather (deferred residual) ------------
// One wave per destination row; 8 slots x 8 lanes; lane loads v8h (16B) of
// the 128B fp16 src row; unroll x2 -> 16 rows in flight. Butterfly-reduce
// over slots. Packed csr: one uint per entry.
//   MODE 0: t1 = fp16(acc)
//   MODE 1: t2 = fp16(acc)
//   MODE 2: out = ((t0+t1+t2 own rows) + acc) * 1/(LAYERS+1)
template <int MODE>
__global__ __launch_bounds__(256) void gather_fused(
    const _Float16* __restrict__ tab,   // gather-source table [item|user]
    _Float16* __restrict__ dst,         // layer output table (MODE<2)
    const _Float16* __restrict__ e0,    // t0 (MODE 2)
    const _Float16* __restrict__ e1,    // t1 (MODE 2)
    float* __restrict__ out,            // fp32 [item_acc | user_acc] (MODE 2)
    const unsigned* __restrict__ csrp,
    const int* __restrict__ row_ptr) {
  int row = blockIdx.x * 4 + (threadIdx.x >> 6);
  if (row >= NROWS) return;
  int lane = threadIdx.x & 63;
  int slot = lane >> 3;          // 0..7
  int c8   = (lane & 7) * 8;     // channel offset 0,8,...,56

  const _Float16* gtab;
  long long own;                 // own-row offset in [item|user] layout
  if (row < N_USERS) {
    gtab = tab;                                        // item side (base 0)
    own  = ITEM_ELEMS + (long long)row * CH;
  } else {
    gtab = tab + ITEM_ELEMS;                           // user side
    own  = (long long)(row - N_USERS) * CH;
  }

  int beg = row_ptr[row], end = row_ptr[row + 1];
  float acc[8];
#pragma unroll
  for (int k = 0; k < 8; ++k) acc[k] = 0.f;
  int j = beg + slot;
  for (; j + 8 < end; j += 16) {
    unsigned p0 = csrp[j];
    unsigned p1 = csrp[j + 8];
    v8h h0 = *(const v8h*)(gtab + (long long)(p0 >> 15) * CH + c8);
    v8h h1 = *(const v8h*)(gtab + (long long)(p1 >> 15) * CH + c8);
    float w0 = w15_to_f(p0);
    float w1 = w15_to_f(p1);
#pragma unroll
    for (int k = 0; k < 8; ++k) acc[k] += w0 * (float)h0[k];
#pragma unroll
    for (int k = 0; k < 8; ++k) acc[k] += w1 * (float)h1[k];
  }
  if (j < end) {
    unsigned p0 = csrp[j];
    float we = w15_to_f(p0);
    v8h h = *(const v8h*)(gtab + (long long)(p0 >> 15) * CH + c8);
#pragma unroll
    for (int k = 0; k < 8; ++k) acc[k] += we * (float)h[k];
  }
#pragma unroll
  for (int off = 8; off < 64; off <<= 1) {
#pragma unroll
    for (int k = 0; k < 8; ++k) acc[k] += __shfl_xor(acc[k], off, 64);
  }
  if (slot == 0) {
    if (MODE < 2) {
      v8h hd;
#pragma unroll
      for (int k = 0; k < 8; ++k) hd[k] = (_Float16)acc[k];
      *(v8h*)(dst + own + c8) = hd;
    } else {
      const float s = 1.0f / (LAYERS + 1);
      v8h a0 = *(const v8h*)(e0 + own + c8);    // fp16(emb)
      v8h a1 = *(const v8h*)(e1 + own + c8);    // fp16(l1)
      v8h a2 = *(const v8h*)(tab + own + c8);   // fp16(l2)  (tab == t2)
      v8f o;
#pragma unroll
      for (int k = 0; k < 8; ++k)
        o[k] = ((float)a0[k] + (float)a1[k] + (float)a2[k] + acc[k]) * s;
      *(v8f*)(out + own + c8) = o;
    }
  }
}

// ---------------- fallback (R1 atomic path) ----------------

__global__ __launch_bounds__(256) void atomic_scatter_kernel(
    const float* __restrict__ src, float* __restrict__ dst,
    const int* __restrict__ u_idx, const int* __restrict__ i_idx,
    const float* __restrict__ w) {
  long long tid = (long long)blockIdx.x * blockDim.x + threadIdx.x;
  int edge = (int)(tid >> 4);
  if (edge >= N_EDGES) return;
  int c = ((int)tid & 15) * 4;
  int ui = u_idx[edge], ii = i_idx[edge];
  float we = w[edge];
  float4 itv = *(const float4*)(src + (long long)ii * CH + c);
  float4 uv  = *(const float4*)(src + ITEM_ELEMS + (long long)ui * CH + c);
  float* ud = dst + ITEM_ELEMS + (long long)ui * CH + c;
  float* id = dst + (long long)ii * CH + c;
  unsafeAtomicAdd(ud + 0, we * itv.x);
  unsafeAtomicAdd(ud + 1, we * itv.y);
  unsafeAtomicAdd(ud + 2, we * itv.z);
  unsafeAtomicAdd(ud + 3, we * itv.w);
  unsafeAtomicAdd(id + 0, we * uv.x);
  unsafeAtomicAdd(id + 1, we * uv.y);
  unsafeAtomicAdd(id + 2, we * uv.z);
  unsafeAtomicAdd(id + 3, we * uv.w);
}

__global__ __launch_bounds__(256) void add_scale_kernel(
    float* __restrict__ acc, const float* __restrict__ add, float s, long long n4) {
  long long i = (long long)blockIdx.x * blockDim.x + threadIdx.x;
  if (i >= n4) return;
  float4 a = ((const float4*)acc)[i];
  float4 b = ((const float4*)add)[i];
  a.x = (a.x + b.x) * s;
  a.y = (a.y + b.y) * s;
  a.z = (a.z + b.z) * s;
  a.w = (a.w + b.w) * s;
  ((float4*)acc)[i] = a;
}

extern "C" void kernel_launch(void* const* d_in, const int* in_sizes, int n_in,
                              void* d_out, int out_size, void* d_ws, size_t ws_size,
                              hipStream_t stream) {
  const float* user_emb = (const float*)d_in[1];
  const float* item_emb = (const float*)d_in[2];
  const int*   edges    = (const int*)d_in[3];
  const int*   u_idx    = edges;            // row 0
  const int*   i_idx    = edges + N_EDGES;  // row 1
  const float* w        = (const float*)d_in[4];

  float* out = (float*)d_out;  // [item_acc | user_acc]

  // workspace layout (4B units) — region sizes identical to prior rounds
  float* buf_a   = (float*)d_ws;                 // TOT_ELEMS (38.4MB)
  float* buf_b   = buf_a + TOT_ELEMS;            // TOT_ELEMS (38.4MB)
  float* csr_rg  = buf_b + TOT_ELEMS;            // 2*NDIR ints (32MB)
  int*   ibase   = (int*)(csr_rg + 2 * (size_t)NDIR);  // 3*NROWS+1+1024 ints
  const size_t needed =
      ((size_t)2 * TOT_ELEMS + 2 * (size_t)NDIR + 3 * (size_t)NROWS + 1 + 1024) * 4;

  // lifetimes:
  //   segkey/segw in buf_a (24MB)    : binning .. win_sort1024
  //   t0/t1 in buf_a (38.4MB)        : cvt_tab .. layers (overwrites seg)
  //   blkfine/bsumsF in buf_b (2MB)  : binning .. win_sort1024
  //   t2 in buf_b (19.2MB)           : layer MODE1 onward
  //   csrp in csr region (16MB)      : win_sort1024 .. layers
  //   row_ptr in ibase               : win_sort1024 .. layers
  int*      segkey  = (int*)buf_a;
  _Float16* segw    = (_Float16*)(segkey + NDIR);
  unsigned* csrp    = (unsigned*)csr_rg;
  int*      row_ptr = ibase;                     // NROWS+1 ints
  int*      blkfine = (int*)buf_b;               // NFB ints (500736)
  int*      bsumsF  = blkfine + NFB;             // 1024
  _Float16* t0 = (_Float16*)buf_a;
  _Float16* t1 = t0 + TOT_ELEMS;
  _Float16* t2 = (_Float16*)buf_b;

  if (ws_size >= needed) {
    // ---- window binning (zero device atomics) ----
    bincnt1024<<<NBLK, 1024, 0, stream>>>(u_idx, i_idx, blkfine);
    const int nbF = (NFB + 511) / 512;  // 978 <= 1024
    scanA512<<<nbF, 512, 0, stream>>>(blkfine, blkfine, bsumsF, NFB);
    scanB_kernel<<<1, 1024, 0, stream>>>(bsumsF, nbF);
    winscanC512<<<nbF, 512, 0, stream>>>(blkfine, bsumsF, NFB);
    const size_t seg_smem = 8192 * 4 + 8192 * 2 + 8192 * 2 + FWIN * 4;
    segwrite1024<<<NBLK, 1024, seg_smem, stream>>>(
        u_idx, i_idx, w, blkfine, segkey, segw);

    // ---- per-window counting sort -> packed CSR (all windows LDS) ----
    win_sort1024<<<FWIN, 1024, 0, stream>>>(
        segkey, segw, blkfine, row_ptr, csrp);

    // ---- fp16 input table (seg dead; overwrite buf_a) ----
    const int cvt_blocks = (int)((TOT_ELEMS / 4 + 255) / 256);
    cvt_tab<<<cvt_blocks, 256, 0, stream>>>(item_emb, user_emb, t0);

    // ---- layers (deferred residual) ----
    const int gather_blocks = (NROWS + 3) / 4;  // 4 rows (waves) per block
    gather_fused<0><<<gather_blocks, 256, 0, stream>>>(
        t0, t1, nullptr, nullptr, nullptr, csrp, row_ptr);
    gather_fused<1><<<gather_blocks, 256, 0, stream>>>(
        t1, t2, nullptr, nullptr, nullptr, csrp, row_ptr);
    gather_fused<2><<<gather_blocks, 256, 0, stream>>>(
        t2, nullptr, t0, t1, out, csrp, row_ptr);
  } else {
    // ---- fallback: R1 atomic scatter ----
    const size_t item_bytes = (size_t)ITEM_ELEMS * sizeof(float);
    const size_t user_bytes = (size_t)USER_ELEMS * sizeof(float);
    hipMemcpyAsync(buf_a,              item_emb, item_bytes, hipMemcpyDeviceToDevice, stream);
    hipMemcpyAsync(buf_a + ITEM_ELEMS, user_emb, user_bytes, hipMemcpyDeviceToDevice, stream);
    hipMemcpyAsync(out,                item_emb, item_bytes, hipMemcpyDeviceToDevice, stream);
    hipMemcpyAsync(out + ITEM_ELEMS,   user_emb, user_bytes, hipMemcpyDeviceToDevice, stream);
    const long long st = (long long)N_EDGES * 16;
    const int sb = (int)((st + 255) / 256);
    const long long n4 = TOT_ELEMS / 4;
    const int add_blocks = (int)((n4 + 255) / 256);
    float* src = buf_a;
    float* dst = buf_b;
    for (int l = 0; l < LAYERS; ++l) {
      hipMemsetAsync(dst, 0, (size_t)TOT_ELEMS * sizeof(float), stream);
      atomic_scatter_kernel<<<sb, 256, 0, stream>>>(src, dst, u_idx, i_idx, w);
      const float s = (l == LAYERS - 1) ? (1.0f / (LAYERS + 1)) : 1.0f;
      add_scale_kernel<<<add_blocks, 256, 0, stream>>>(out, dst, s, n4);
      float* t = src; src = dst; dst = t;
    }
  }
}